// Round 2
// baseline (3666.874 us; speedup 1.0000x reference)
//
#include <hip/hip_runtime.h>
#include <math.h>

// Fully-fused CapsuleNet forward. One wave per batch element; h in LDS (4KB);
// x_hat recomputed from W on the fly each routing iteration (3 passes/layer,
// provably minimal); vsum (the affine-logit state) lives in registers.
// Zero workspace. W streamed through L2/L3 (10.5 MB total, L3-resident).
//
// Lane mapping per layer: LPO = Do/16 lanes per output capsule o;
// lane l -> o = l/LPO, d-chunk = (l%LPO)*16 .. +15. ACT = O*LPO <= 64.

template<int I, int Di, int O, int Do, bool FINAL>
__device__ __forceinline__ void capsule_layer(const float* __restrict__ W,
                                              float* __restrict__ hl,
                                              float* __restrict__ out,
                                              int e, int l) {
    constexpr int LPO = Do / 16;
    constexpr int ACT = O * LPO;
    static_assert(ACT <= 64, "lane mapping");
    const int o  = l / LPO;
    const int d0 = (l % LPO) * 16;
    const bool act = (l < ACT);

    float vs[16];                       // running sum of squash outputs (logit state)
    #pragma unroll
    for (int j = 0; j < 16; ++j) vs[j] = 0.f;

    for (int r = 0; r < 3; ++r) {
        float sacc[16];
        #pragma unroll
        for (int j = 0; j < 16; ++j) sacc[j] = 0.f;

        for (int i = 0; i < I; ++i) {
            if ((i & 15) == 0) __syncthreads();   // keep waves clustered for L1 reuse
            float xh[16];
            #pragma unroll
            for (int j = 0; j < 16; ++j) xh[j] = 0.f;
            if (act) {
                const float* wb = W + ((size_t)(o * I + i) * Do + d0) * Di;
                #pragma unroll
                for (int j = 0; j < 16; ++j) {
                    const float4* wr = (const float4*)(wb + j * Di);
                    float acc = 0.f;
                    #pragma unroll
                    for (int c4 = 0; c4 < Di / 4; ++c4) {
                        float4 wv = wr[c4];
                        float4 hv = *(const float4*)(hl + i * Di + c4 * 4);  // LDS broadcast
                        acc += wv.x * hv.x + wv.y * hv.y + wv.z * hv.z + wv.w * hv.w;
                    }
                    xh[j] = acc;
                }
            }
            float cc;
            if (r == 0) {
                cc = 1.0f;              // uniform c; the 1/O factor is folded in below
            } else {
                float lp = 0.f;
                #pragma unroll
                for (int j = 0; j < 16; ++j) lp += vs[j] * xh[j];
                if constexpr (LPO >= 2) lp += __shfl_xor(lp, 1, 64);
                if constexpr (LPO >= 4) lp += __shfl_xor(lp, 2, 64);
                float ev = act ? __expf(lp) : 0.f;
                float tot = ev;                    // butterfly over all 64 lanes:
                tot += __shfl_xor(tot, 1, 64);     // counts each o exactly LPO times
                tot += __shfl_xor(tot, 2, 64);
                tot += __shfl_xor(tot, 4, 64);
                tot += __shfl_xor(tot, 8, 64);
                tot += __shfl_xor(tot, 16, 64);
                tot += __shfl_xor(tot, 32, 64);
                cc = ev * (float)LPO / tot;
            }
            #pragma unroll
            for (int j = 0; j < 16; ++j) sacc[j] += cc * xh[j];
        }

        if (r == 0) {
            #pragma unroll
            for (int j = 0; j < 16; ++j) sacc[j] *= (1.0f / O);
        }
        // squash
        float n2 = 0.f;
        #pragma unroll
        for (int j = 0; j < 16; ++j) n2 += sacc[j] * sacc[j];
        if constexpr (LPO >= 2) n2 += __shfl_xor(n2, 1, 64);
        if constexpr (LPO >= 4) n2 += __shfl_xor(n2, 2, 64);
        float nrm   = sqrtf(n2);
        float scale = n2 / ((1.f + n2) * (nrm + 1e-8f));

        if (r < 2) {
            #pragma unroll
            for (int j = 0; j < 16; ++j) vs[j] += scale * sacc[j];   // vs starts at 0
        } else {
            if constexpr (FINAL) {
                float q = 0.f;
                #pragma unroll
                for (int j = 0; j < 16; ++j) { float vj = scale * sacc[j]; q += vj * vj; }
                if constexpr (LPO >= 2) q += __shfl_xor(q, 1, 64);
                if constexpr (LPO >= 4) q += __shfl_xor(q, 2, 64);
                if (act && (l % LPO) == 0) out[(size_t)e * O + o] = sqrtf(q);
            } else {
                __syncthreads();        // all reads of hl done; safe to overwrite
                if (act) {
                    #pragma unroll
                    for (int j = 0; j < 16; ++j) hl[o * Do + d0 + j] = scale * sacc[j];
                }
                __syncthreads();        // make writes visible (and LDS-ordered)
            }
        }
    }
}

__global__ __launch_bounds__(256) void caps_fused(const float* __restrict__ x,
                                                  const float* __restrict__ W0,
                                                  const float* __restrict__ W1,
                                                  const float* __restrict__ W2,
                                                  float* __restrict__ out) {
    __shared__ float hsh[4][1024];
    const int w = threadIdx.x >> 6;
    const int l = threadIdx.x & 63;
    const int e = blockIdx.x * 4 + w;       // batch element owned by this wave
    float* hl = hsh[w];

    // load h0 = x[e] (1024 floats) coalesced
    const float4* xr = (const float4*)(x + (size_t)e * 1024);
    float4* h4 = (float4*)hl;
    #pragma unroll
    for (int k = 0; k < 4; ++k) h4[l + 64 * k] = xr[l + 64 * k];
    __syncthreads();

    capsule_layer<128, 8, 64, 16, false>(W0, hl, out, e, l);
    capsule_layer<64, 16, 32, 32, false>(W1, hl, out, e, l);
    capsule_layer<32, 32, 10, 64, true >(W2, hl, out, e, l);
}

extern "C" void kernel_launch(void* const* d_in, const int* in_sizes, int n_in,
                              void* d_out, int out_size, void* d_ws, size_t ws_size,
                              hipStream_t stream) {
    const float* x  = (const float*)d_in[0];   // [1024,1024]
    const float* W0 = (const float*)d_in[1];   // [64,128,16,8]
    const float* W1 = (const float*)d_in[2];   // [32,64,32,16]
    const float* W2 = (const float*)d_in[3];   // [10,32,64,32]
    float* out = (float*)d_out;                // [1024,10]

    caps_fused<<<256, 256, 0, stream>>>(x, W0, W1, W2, out);
}